// Round 1
// baseline (5588.396 us; speedup 1.0000x reference)
//
#include <hip/hip_runtime.h>

#define NG 4096
#define NP 512
#define BSZ 128
#define NT 100

typedef unsigned short u16;
typedef __attribute__((ext_vector_type(8))) short short8;
typedef __attribute__((ext_vector_type(4))) short short4v;
typedef __attribute__((ext_vector_type(4))) float f32x4;

__device__ inline u16 f2bf(float x) {
  union { float f; unsigned u; } c; c.f = x;
  unsigned r = c.u + 0x7fffu + ((c.u >> 16) & 1u);
  return (u16)(r >> 16);
}
__device__ inline float bf2f(u16 b) {
  union { unsigned u; float f; } c; c.u = ((unsigned)b) << 16; return c.f;
}
__device__ inline f32x4 mfma_bf16(short8 a, short8 b, f32x4 c) {
  return __builtin_amdgcn_mfma_f32_16x16x32_bf16(a, b, c, 0, 0, 0);
}

// ---------------- one-time prep kernels ----------------

__global__ __launch_bounds__(256) void split_kernel(
    const float* __restrict__ src, u16* __restrict__ hi, u16* __restrict__ lo, int n4)
{
  int i = blockIdx.x * 256 + threadIdx.x;
  if (i >= n4) return;
  const float4 x = ((const float4*)src)[i];
  u16 h0 = f2bf(x.x), h1 = f2bf(x.y), h2 = f2bf(x.z), h3 = f2bf(x.w);
  short4v H = { (short)h0, (short)h1, (short)h2, (short)h3 };
  short4v L = { (short)f2bf(x.x - bf2f(h0)), (short)f2bf(x.y - bf2f(h1)),
                (short)f2bf(x.z - bf2f(h2)), (short)f2bf(x.w - bf2f(h3)) };
  *(short4v*)&hi[(size_t)i * 4] = H;
  *(short4v*)&lo[(size_t)i * 4] = L;
}

__global__ __launch_bounds__(256) void conv_kernel(
    const float* __restrict__ src, u16* __restrict__ dst, int n4)
{
  int i = blockIdx.x * 256 + threadIdx.x;
  if (i >= n4) return;
  const float4 x = ((const float4*)src)[i];
  short4v H = { (short)f2bf(x.x), (short)f2bf(x.y), (short)f2bf(x.z), (short)f2bf(x.w) };
  *(short4v*)&dst[(size_t)i * 4] = H;
}

// h0 = p0 @ W_enc^T (fp32), stored as hi/lo bf16 split
__global__ __launch_bounds__(256) void encode_kernel(
    const float* __restrict__ p0, const float* __restrict__ wenc,
    u16* __restrict__ h0hi, u16* __restrict__ h0lo)
{
  __shared__ float sp[NP];
  const int b = blockIdx.y;
  const int g = blockIdx.x * 256 + threadIdx.x;
  for (int i = threadIdx.x; i < NP; i += 256) sp[i] = p0[(size_t)b * NP + i];
  __syncthreads();
  const float4* wr = (const float4*)(wenc + (size_t)g * NP);
  float acc = 0.f;
  #pragma unroll 8
  for (int p4 = 0; p4 < NP / 4; ++p4) {
    float4 ww = wr[p4];
    acc += ww.x * sp[4*p4] + ww.y * sp[4*p4+1] + ww.z * sp[4*p4+2] + ww.w * sp[4*p4+3];
  }
  u16 hb = f2bf(acc);
  h0hi[(size_t)b * NG + g] = hb;
  h0lo[(size_t)b * NG + g] = f2bf(acc - bf2f(hb));
}

// ---------------- recurrent step ----------------
// h_new = relu(v[:,t,:] @ W_ih^T + h_old @ W_hh^T)
// hi/lo bf16 3-product scheme: D += Ah*Bh + Ah*Bl + Al*Bh  (fp32 accum)
// tile: 32 (batch) x 64 (g), K-chunk 64, 4 waves, grid (4, 64)
__global__ __launch_bounds__(256, 1) void step_kernel(
    const u16* __restrict__ whh_hi, const u16* __restrict__ whh_lo,
    const u16* __restrict__ ahi, const u16* __restrict__ alo,
    const float* __restrict__ v, const float* __restrict__ wih,
    u16* __restrict__ ohi, u16* __restrict__ olo, int t)
{
  __shared__ u16 lAh[32][72], lAl[32][72];   // +8 pad: 144B rows, conflict-benign
  __shared__ u16 lBh[64][72], lBl[64][72];
  const int tid = threadIdx.x;
  const int w = tid >> 6, lane = tid & 63;
  const int m0 = blockIdx.x * 32, n0 = blockIdx.y * 64;

  f32x4 acc0 = {0.f, 0.f, 0.f, 0.f};
  f32x4 acc1 = {0.f, 0.f, 0.f, 0.f};

  const int srow = tid >> 3;         // 0..31
  const int skk  = (tid & 7) * 8;    // 0..56
  const u16* gA_h  = ahi    + (size_t)(m0 + srow) * NG + skk;
  const u16* gA_l  = alo    + (size_t)(m0 + srow) * NG + skk;
  const u16* gB_h0 = whh_hi + (size_t)(n0 + srow) * NG + skk;
  const u16* gB_h1 = whh_hi + (size_t)(n0 + srow + 32) * NG + skk;
  const u16* gB_l0 = whh_lo + (size_t)(n0 + srow) * NG + skk;
  const u16* gB_l1 = whh_lo + (size_t)(n0 + srow + 32) * NG + skk;

  // MFMA 16x16x32 fragment addressing:
  // A: row = lane&15 (+row-tile), k = (lane>>4)*8 + j
  // B: col = lane&15 (+col-tile), k = (lane>>4)*8 + j   (B[k][col] = Whh[col][k])
  const int frow = 16 * (w & 1) + (lane & 15);
  const int fk   = (lane >> 4) * 8;
  const int fcol = 32 * (w >> 1) + (lane & 15);

  for (int k0 = 0; k0 < NG; k0 += 64) {
    *(short8*)&lAh[srow][skk]      = *(const short8*)(gA_h + k0);
    *(short8*)&lAl[srow][skk]      = *(const short8*)(gA_l + k0);
    *(short8*)&lBh[srow][skk]      = *(const short8*)(gB_h0 + k0);
    *(short8*)&lBh[srow + 32][skk] = *(const short8*)(gB_h1 + k0);
    *(short8*)&lBl[srow][skk]      = *(const short8*)(gB_l0 + k0);
    *(short8*)&lBl[srow + 32][skk] = *(const short8*)(gB_l1 + k0);
    __syncthreads();
    #pragma unroll
    for (int kk = 0; kk < 64; kk += 32) {
      short8 a_h = *(const short8*)&lAh[frow][kk + fk];
      short8 a_l = *(const short8*)&lAl[frow][kk + fk];
      short8 b0h = *(const short8*)&lBh[fcol][kk + fk];
      short8 b0l = *(const short8*)&lBl[fcol][kk + fk];
      short8 b1h = *(const short8*)&lBh[fcol + 16][kk + fk];
      short8 b1l = *(const short8*)&lBl[fcol + 16][kk + fk];
      acc0 = mfma_bf16(a_h, b0h, acc0);
      acc1 = mfma_bf16(a_h, b1h, acc1);
      acc0 = mfma_bf16(a_h, b0l, acc0);
      acc1 = mfma_bf16(a_h, b1l, acc1);
      acc0 = mfma_bf16(a_l, b0h, acc0);
      acc1 = mfma_bf16(a_l, b1h, acc1);
    }
    __syncthreads();
  }

  // epilogue: + vin bias, relu, hi/lo split store
  // C/D frag: col = lane&15, row = (lane>>4)*4 + j   [verified mapping]
  const int brow0 = m0 + 16 * (w & 1) + (lane >> 4) * 4;
  const int gcol0 = n0 + 32 * (w >> 1) + (lane & 15);
  const float2* wih2 = (const float2*)wih;
  const float2 wg0 = wih2[gcol0];
  const float2 wg1 = wih2[gcol0 + 16];
  #pragma unroll
  for (int j = 0; j < 4; ++j) {
    const int b = brow0 + j;
    const float2 vb = *(const float2*)&v[((size_t)b * NT + t) * 2];
    float x0 = acc0[j] + vb.x * wg0.x + vb.y * wg0.y;
    float x1 = acc1[j] + vb.x * wg1.x + vb.y * wg1.y;
    x0 = fmaxf(x0, 0.f);
    x1 = fmaxf(x1, 0.f);
    u16 h0 = f2bf(x0), h1 = f2bf(x1);
    ohi[(size_t)b * NG + gcol0]      = h0;
    ohi[(size_t)b * NG + gcol0 + 16] = h1;
    olo[(size_t)b * NG + gcol0]      = f2bf(x0 - bf2f(h0));
    olo[(size_t)b * NG + gcol0 + 16] = f2bf(x1 - bf2f(h1));
  }
}

// ---------------- decode + fused log_softmax ----------------
// preds[r][p] = sum_g hs[r][g] * Wdec[p][g]; block = 64 rows x all 512 cols
__global__ __launch_bounds__(512, 1) void decode_kernel(
    const u16* __restrict__ hsrc, const u16* __restrict__ wdec_b,
    float* __restrict__ out, int rows, int tsel)
{
  __shared__ u16 lA[64][40];
  __shared__ u16 lB[512][40];
  __shared__ float redm[2][64];
  __shared__ float reds[2][64];
  const int tid = threadIdx.x;
  const int w = tid >> 6, lane = tid & 63;
  const int r0 = blockIdx.x * 64;
  const int rt = w & 3, ch = w >> 2;   // row-tile, col-half

  f32x4 z = {0.f, 0.f, 0.f, 0.f};
  f32x4 acc[16];
  #pragma unroll
  for (int i = 0; i < 16; ++i) acc[i] = z;

  const int arow = tid >> 3, akk = (tid & 7) * 4;
  const int brow = tid >> 2, bkk = (tid & 3) * 8;
  const u16* gA  = hsrc   + (size_t)(r0 + arow) * NG + akk;
  const u16* gB0 = wdec_b + (size_t)brow * NG + bkk;

  const int frow = 16 * rt + (lane & 15);
  const int fk = (lane >> 4) * 8;
  const int cbase = 256 * ch + (lane & 15);

  for (int k0 = 0; k0 < NG; k0 += 32) {
    *(short4v*)&lA[arow][akk] = *(const short4v*)(gA + k0);
    #pragma unroll
    for (int p = 0; p < 4; ++p)
      *(short8*)&lB[brow + 128 * p][bkk] = *(const short8*)(gB0 + (size_t)128 * p * NG + k0);
    __syncthreads();
    short8 af = *(const short8*)&lA[frow][fk];
    #pragma unroll
    for (int ct = 0; ct < 16; ++ct) {
      short8 bf = *(const short8*)&lB[cbase + 16 * ct][fk];
      acc[ct] = mfma_bf16(af, bf, acc[ct]);
    }
    __syncthreads();
  }

  const int q = lane >> 4;
  const int rloc0 = 16 * rt + q * 4;
  float mx[4], sm[4];
  #pragma unroll
  for (int j = 0; j < 4; ++j) {
    float m = -3.4e38f;
    #pragma unroll
    for (int ct = 0; ct < 16; ++ct) m = fmaxf(m, acc[ct][j]);
    mx[j] = m;
  }
  #pragma unroll
  for (int d = 1; d < 16; d <<= 1) {
    #pragma unroll
    for (int j = 0; j < 4; ++j) mx[j] = fmaxf(mx[j], __shfl_xor(mx[j], d));
  }
  if ((lane & 15) == 0) {
    #pragma unroll
    for (int j = 0; j < 4; ++j) redm[ch][rloc0 + j] = mx[j];
  }
  __syncthreads();
  float M[4];
  #pragma unroll
  for (int j = 0; j < 4; ++j) M[j] = fmaxf(redm[0][rloc0 + j], redm[1][rloc0 + j]);
  #pragma unroll
  for (int j = 0; j < 4; ++j) {
    float s = 0.f;
    #pragma unroll
    for (int ct = 0; ct < 16; ++ct) s += __expf(acc[ct][j] - M[j]);
    sm[j] = s;
  }
  #pragma unroll
  for (int d = 1; d < 16; d <<= 1) {
    #pragma unroll
    for (int j = 0; j < 4; ++j) sm[j] += __shfl_xor(sm[j], d);
  }
  if ((lane & 15) == 0) {
    #pragma unroll
    for (int j = 0; j < 4; ++j) reds[ch][rloc0 + j] = sm[j];
  }
  __syncthreads();
  #pragma unroll
  for (int j = 0; j < 4; ++j) {
    const int r = r0 + rloc0 + j;
    const int tt = (tsel < 0) ? (r >> 7) : tsel;
    const int b  = (tsel < 0) ? (r & 127) : r;
    const float lg = M[j] + __logf(reds[0][rloc0 + j] + reds[1][rloc0 + j]);
    float* orow = out + ((size_t)b * NT + tt) * NP + cbase;
    #pragma unroll
    for (int ct = 0; ct < 16; ++ct) orow[16 * ct] = acc[ct][j] - lg;
  }
}

// ---------------- host ----------------

extern "C" void kernel_launch(void* const* d_in, const int* in_sizes, int n_in,
                              void* d_out, int out_size, void* d_ws, size_t ws_size,
                              hipStream_t stream)
{
  const float* v    = (const float*)d_in[0];
  const float* p0   = (const float*)d_in[1];
  const float* wenc = (const float*)d_in[2];
  const float* wih  = (const float*)d_in[3];
  const float* whh  = (const float*)d_in[4];
  const float* wdec = (const float*)d_in[5];
  float* out = (float*)d_out;
  char* ws = (char*)d_ws;

  u16* whh_hi = (u16*)(ws);                       // 33,554,432
  u16* whh_lo = (u16*)(ws + 33554432);            // 33,554,432
  u16* wdec_b = (u16*)(ws + 67108864);            //  4,194,304
  u16* h0hi   = (u16*)(ws + 71303168);            //  1,048,576
  u16* h0lo   = (u16*)(ws + 72351744);            //  1,048,576
  u16* hlo0   = (u16*)(ws + 73400320);            //  1,048,576
  u16* hlo1   = (u16*)(ws + 74448896);            //  1,048,576
  u16* hs     = (u16*)(ws + 75497472);            // 104,857,600 (big) / 2 MB ping-pong (small)
  const size_t BNG = (size_t)BSZ * NG;
  const bool big = ws_size >= 180355072ull;

  split_kernel<<<dim3(16384), dim3(256), 0, stream>>>(whh, whh_hi, whh_lo, 4194304);
  conv_kernel<<<dim3(2048), dim3(256), 0, stream>>>(wdec, wdec_b, 524288);
  encode_kernel<<<dim3(16, 128), dim3(256), 0, stream>>>(p0, wenc, h0hi, h0lo);

  for (int t = 0; t < NT; ++t) {
    const u16 *ahi, *alo;
    u16 *ohi, *olo;
    if (t == 0) { ahi = h0hi; alo = h0lo; }
    else {
      ahi = big ? hs + (size_t)(t - 1) * BNG : hs + (size_t)((t - 1) & 1) * BNG;
      alo = (t & 1) ? hlo0 : hlo1;
    }
    ohi = big ? hs + (size_t)t * BNG : hs + (size_t)(t & 1) * BNG;
    olo = (t & 1) ? hlo1 : hlo0;
    step_kernel<<<dim3(4, 64), dim3(256), 0, stream>>>(whh_hi, whh_lo, ahi, alo, v, wih, ohi, olo, t);
    if (!big)
      decode_kernel<<<dim3(2), dim3(512), 0, stream>>>(ohi, wdec_b, out, 128, t);
  }
  if (big)
    decode_kernel<<<dim3(200), dim3(512), 0, stream>>>(hs, wdec_b, out, 12800, -1);
}

// Round 2
// 2483.486 us; speedup vs baseline: 2.2502x; 2.2502x over previous
//
#include <hip/hip_runtime.h>

#define NG 4096
#define NP 512
#define BSZ 128
#define NT 100
#define KS 8
#define KBLK 512
#define KC 64

typedef unsigned short u16;
typedef __attribute__((ext_vector_type(8))) short short8;
typedef __attribute__((ext_vector_type(4))) short short4v;
typedef __attribute__((ext_vector_type(4))) float f32x4;

__device__ inline u16 f2bf(float x) {
  union { float f; unsigned u; } c; c.f = x;
  unsigned r = c.u + 0x7fffu + ((c.u >> 16) & 1u);
  return (u16)(r >> 16);
}
__device__ inline float bf2f(u16 b) {
  union { unsigned u; float f; } c; c.u = ((unsigned)b) << 16; return c.f;
}
__device__ inline f32x4 mfma_bf16(short8 a, short8 b, f32x4 c) {
  return __builtin_amdgcn_mfma_f32_16x16x32_bf16(a, b, c, 0, 0, 0);
}
__device__ __forceinline__ void gload16(const void* g, void* l) {
  __builtin_amdgcn_global_load_lds(
      (const __attribute__((address_space(1))) void*)g,
      (__attribute__((address_space(3))) void*)l, 16, 0, 0);
}

// ---------------- one-time prep kernels ----------------

__global__ __launch_bounds__(256) void split_kernel(
    const float* __restrict__ src, u16* __restrict__ hi, u16* __restrict__ lo, int n4)
{
  int i = blockIdx.x * 256 + threadIdx.x;
  if (i >= n4) return;
  const float4 x = ((const float4*)src)[i];
  u16 h0 = f2bf(x.x), h1 = f2bf(x.y), h2 = f2bf(x.z), h3 = f2bf(x.w);
  short4v H = { (short)h0, (short)h1, (short)h2, (short)h3 };
  short4v L = { (short)f2bf(x.x - bf2f(h0)), (short)f2bf(x.y - bf2f(h1)),
                (short)f2bf(x.z - bf2f(h2)), (short)f2bf(x.w - bf2f(h3)) };
  *(short4v*)&hi[(size_t)i * 4] = H;
  *(short4v*)&lo[(size_t)i * 4] = L;
}

__global__ __launch_bounds__(256) void conv_kernel(
    const float* __restrict__ src, u16* __restrict__ dst, int n4)
{
  int i = blockIdx.x * 256 + threadIdx.x;
  if (i >= n4) return;
  const float4 x = ((const float4*)src)[i];
  short4v H = { (short)f2bf(x.x), (short)f2bf(x.y), (short)f2bf(x.z), (short)f2bf(x.w) };
  *(short4v*)&dst[(size_t)i * 4] = H;
}

// h0 = p0 @ W_enc^T (fp32), stored as hi/lo bf16 split
__global__ __launch_bounds__(256) void encode_kernel(
    const float* __restrict__ p0, const float* __restrict__ wenc,
    u16* __restrict__ h0hi, u16* __restrict__ h0lo)
{
  __shared__ float sp[NP];
  const int b = blockIdx.y;
  const int g = blockIdx.x * 256 + threadIdx.x;
  for (int i = threadIdx.x; i < NP; i += 256) sp[i] = p0[(size_t)b * NP + i];
  __syncthreads();
  const float4* wr = (const float4*)(wenc + (size_t)g * NP);
  float acc = 0.f;
  #pragma unroll 8
  for (int p4 = 0; p4 < NP / 4; ++p4) {
    float4 ww = wr[p4];
    acc += ww.x * sp[4*p4] + ww.y * sp[4*p4+1] + ww.z * sp[4*p4+2] + ww.w * sp[4*p4+3];
  }
  u16 hb = f2bf(acc);
  h0hi[(size_t)b * NG + g] = hb;
  h0lo[(size_t)b * NG + g] = f2bf(acc - bf2f(hb));
}

// ---------------- recurrent step: K-split GEMM ----------------
// partial[ks] += A(128 x K512) * B(128 x K512)^T  for this block's n-tile.
// hi/lo bf16 3-product: D += Ah*Bh + Ah*Bl + Al*Bh (fp32 accum).
// grid (KS=8, 32); block 512 thr = 8 waves (4M x 2N), wave tile 32x64.
// LDS per buffer (64 KB): [Ahi 16K][Alo 16K][Bhi 16K][Blo 16K], each
// [128 rows][128 B], XOR-swizzled on the GLOBAL source (rule #21):
// LDS[row][x] = G[row][colbase + (x ^ ((row&7)<<4))]
__global__ __launch_bounds__(512, 2) void step_gemm(
    const u16* __restrict__ whh_hi, const u16* __restrict__ whh_lo,
    const u16* __restrict__ ahi, const u16* __restrict__ alo,
    float* __restrict__ part)
{
  __shared__ __align__(128) char lds[2 * 65536];
  const int tid = threadIdx.x;
  const int w = tid >> 6, lane = tid & 63;
  const int ks = blockIdx.x;
  const int n0 = blockIdx.y * 128;
  const int k0 = ks * KBLK;

  // staging roles: waves 0-1 Ahi, 2-3 Alo, 4-5 Bhi, 6-7 Blo
  const int arr  = w >> 1;
  const int lrow = lane >> 3;                          // row&7 of this lane's row
  const int soff = ((lane & 7) * 16) ^ (lrow << 4);    // swizzled byte-in-row
  const char* gb = (const char*)((arr == 0) ? ahi : (arr == 1) ? alo
                                : (arr == 2) ? whh_hi : whh_lo);
  const int growbase = ((arr >= 2) ? n0 : 0) + (w & 1) * 64 + lrow;
  char* ldsw = (char*)lds + arr * 16384 + (w & 1) * 8192;

  // frag addressing (16x16x32): A row=lane&15,k=8*(lane>>4)+j ; B col same; verified r1
  const int wm = w & 3, wn = w >> 2;
  const int frow = wm * 32 + (lane & 15);
  const int fcol = wn * 64 + (lane & 15);
  const int fq   = (lane >> 4) * 16;
  const int swA  = (lane & 7) << 4;   // (frow&7)<<4 == (fcol&7)<<4 == (lane&7)<<4

  f32x4 acc[2][4] = {};

  auto stage = [&](int buf, int c) {
    const size_t kb = (size_t)(k0 + c * KC) * 2 + soff;
    char* lb = ldsw + buf * 65536;
    #pragma unroll
    for (int j = 0; j < 8; ++j) {
      gload16(gb + (size_t)(growbase + j * 8) * (NG * 2) + kb, lb + j * 1024);
    }
  };
  auto compute = [&](int buf) {
    const char* base = (const char*)lds + buf * 65536;
    const char* LAh = base;
    const char* LAl = base + 16384;
    const char* LBh = base + 32768;
    const char* LBl = base + 49152;
    #pragma unroll
    for (int kk = 0; kk < 2; ++kk) {
      const int kb = (kk * 64 + fq) ^ swA;
      short8 ah0 = *(const short8*)(LAh + frow * 128 + kb);
      short8 ah1 = *(const short8*)(LAh + (frow + 16) * 128 + kb);
      short8 al0 = *(const short8*)(LAl + frow * 128 + kb);
      short8 al1 = *(const short8*)(LAl + (frow + 16) * 128 + kb);
      #pragma unroll
      for (int nf = 0; nf < 4; ++nf) {
        const int co = (fcol + nf * 16) * 128 + kb;
        short8 bh = *(const short8*)(LBh + co);
        short8 bl = *(const short8*)(LBl + co);
        acc[0][nf] = mfma_bf16(ah0, bh, acc[0][nf]);
        acc[1][nf] = mfma_bf16(ah1, bh, acc[1][nf]);
        acc[0][nf] = mfma_bf16(ah0, bl, acc[0][nf]);
        acc[1][nf] = mfma_bf16(ah1, bl, acc[1][nf]);
        acc[0][nf] = mfma_bf16(al0, bh, acc[0][nf]);
        acc[1][nf] = mfma_bf16(al1, bh, acc[1][nf]);
      }
    }
  };

  stage(0, 0);
  __syncthreads();
  #pragma unroll 1
  for (int c = 0; c < 8; ++c) {
    if (c < 7) stage((c + 1) & 1, c + 1);
    compute(c & 1);
    __syncthreads();
  }

  // epilogue: f32 partial store. C/D: col=lane&15, row=4*(lane>>4)+j (verified r1)
  float* po = part + (size_t)ks * (BSZ * NG);
  const int crow = wm * 32 + (lane >> 4) * 4;
  const int ccol = n0 + wn * 64 + (lane & 15);
  #pragma unroll
  for (int mf = 0; mf < 2; ++mf) {
    #pragma unroll
    for (int j = 0; j < 4; ++j) {
      float* pr = po + (size_t)(crow + mf * 16 + j) * NG + ccol;
      #pragma unroll
      for (int nf = 0; nf < 4; ++nf) pr[nf * 16] = acc[mf][nf][j];
    }
  }
}

// sum KS partials + vin bias + relu + hi/lo split
__global__ __launch_bounds__(256) void step_reduce(
    const float* __restrict__ part, const float* __restrict__ v,
    const float* __restrict__ wih, u16* __restrict__ ohi, u16* __restrict__ olo, int t)
{
  const int i = blockIdx.x * 256 + threadIdx.x;   // 131072 threads, 4 outputs each
  const int b = i >> 10;
  const int g = (i & 1023) * 4;
  const float4* p = (const float4*)part + ((size_t)b * NG + g) / 4;
  float4 s = p[0];
  #pragma unroll
  for (int ksl = 1; ksl < KS; ++ksl) {
    float4 q = p[(size_t)ksl * (BSZ * NG / 4)];
    s.x += q.x; s.y += q.y; s.z += q.z; s.w += q.w;
  }
  const float2 vb = *(const float2*)&v[((size_t)b * NT + t) * 2];
  const float4 w01 = *(const float4*)&wih[(size_t)g * 2];
  const float4 w23 = *(const float4*)&wih[(size_t)g * 2 + 4];
  float x0 = fmaxf(s.x + vb.x * w01.x + vb.y * w01.y, 0.f);
  float x1 = fmaxf(s.y + vb.x * w01.z + vb.y * w01.w, 0.f);
  float x2 = fmaxf(s.z + vb.x * w23.x + vb.y * w23.y, 0.f);
  float x3 = fmaxf(s.w + vb.x * w23.z + vb.y * w23.w, 0.f);
  u16 h0 = f2bf(x0), h1 = f2bf(x1), h2 = f2bf(x2), h3 = f2bf(x3);
  short4v H = { (short)h0, (short)h1, (short)h2, (short)h3 };
  short4v L = { (short)f2bf(x0 - bf2f(h0)), (short)f2bf(x1 - bf2f(h1)),
                (short)f2bf(x2 - bf2f(h2)), (short)f2bf(x3 - bf2f(h3)) };
  *(short4v*)&ohi[(size_t)b * NG + g] = H;
  *(short4v*)&olo[(size_t)b * NG + g] = L;
}

// ---------------- decode + fused log_softmax (unchanged, verified r1) ----------------
__global__ __launch_bounds__(512, 1) void decode_kernel(
    const u16* __restrict__ hsrc, const u16* __restrict__ wdec_b,
    float* __restrict__ out, int rows, int tsel)
{
  __shared__ u16 lA[64][40];
  __shared__ u16 lB[512][40];
  __shared__ float redm[2][64];
  __shared__ float reds[2][64];
  const int tid = threadIdx.x;
  const int w = tid >> 6, lane = tid & 63;
  const int r0 = blockIdx.x * 64;
  const int rt = w & 3, ch = w >> 2;

  f32x4 z = {0.f, 0.f, 0.f, 0.f};
  f32x4 acc[16];
  #pragma unroll
  for (int i = 0; i < 16; ++i) acc[i] = z;

  const int arow = tid >> 3, akk = (tid & 7) * 4;
  const int brow = tid >> 2, bkk = (tid & 3) * 8;
  const u16* gA  = hsrc   + (size_t)(r0 + arow) * NG + akk;
  const u16* gB0 = wdec_b + (size_t)brow * NG + bkk;

  const int frow = 16 * rt + (lane & 15);
  const int fk = (lane >> 4) * 8;
  const int cbase = 256 * ch + (lane & 15);

  for (int k0 = 0; k0 < NG; k0 += 32) {
    *(short4v*)&lA[arow][akk] = *(const short4v*)(gA + k0);
    #pragma unroll
    for (int p = 0; p < 4; ++p)
      *(short8*)&lB[brow + 128 * p][bkk] = *(const short8*)(gB0 + (size_t)128 * p * NG + k0);
    __syncthreads();
    short8 af = *(const short8*)&lA[frow][fk];
    #pragma unroll
    for (int ct = 0; ct < 16; ++ct) {
      short8 bf = *(const short8*)&lB[cbase + 16 * ct][fk];
      acc[ct] = mfma_bf16(af, bf, acc[ct]);
    }
    __syncthreads();
  }

  const int q = lane >> 4;
  const int rloc0 = 16 * rt + q * 4;
  float mx[4], sm[4];
  #pragma unroll
  for (int j = 0; j < 4; ++j) {
    float m = -3.4e38f;
    #pragma unroll
    for (int ct = 0; ct < 16; ++ct) m = fmaxf(m, acc[ct][j]);
    mx[j] = m;
  }
  #pragma unroll
  for (int d = 1; d < 16; d <<= 1) {
    #pragma unroll
    for (int j = 0; j < 4; ++j) mx[j] = fmaxf(mx[j], __shfl_xor(mx[j], d));
  }
  if ((lane & 15) == 0) {
    #pragma unroll
    for (int j = 0; j < 4; ++j) redm[ch][rloc0 + j] = mx[j];
  }
  __syncthreads();
  float M[4];
  #pragma unroll
  for (int j = 0; j < 4; ++j) M[j] = fmaxf(redm[0][rloc0 + j], redm[1][rloc0 + j]);
  #pragma unroll
  for (int j = 0; j < 4; ++j) {
    float s = 0.f;
    #pragma unroll
    for (int ct = 0; ct < 16; ++ct) s += __expf(acc[ct][j] - M[j]);
    sm[j] = s;
  }
  #pragma unroll
  for (int d = 1; d < 16; d <<= 1) {
    #pragma unroll
    for (int j = 0; j < 4; ++j) sm[j] += __shfl_xor(sm[j], d);
  }
  if ((lane & 15) == 0) {
    #pragma unroll
    for (int j = 0; j < 4; ++j) reds[ch][rloc0 + j] = sm[j];
  }
  __syncthreads();
  #pragma unroll
  for (int j = 0; j < 4; ++j) {
    const int r = r0 + rloc0 + j;
    const int tt = (tsel < 0) ? (r >> 7) : tsel;
    const int b  = (tsel < 0) ? (r & 127) : r;
    const float lg = M[j] + __logf(reds[0][rloc0 + j] + reds[1][rloc0 + j]);
    float* orow = out + ((size_t)b * NT + tt) * NP + cbase;
    #pragma unroll
    for (int ct = 0; ct < 16; ++ct) orow[16 * ct] = acc[ct][j] - lg;
  }
}

// ---------------- host ----------------

extern "C" void kernel_launch(void* const* d_in, const int* in_sizes, int n_in,
                              void* d_out, int out_size, void* d_ws, size_t ws_size,
                              hipStream_t stream)
{
  const float* v    = (const float*)d_in[0];
  const float* p0   = (const float*)d_in[1];
  const float* wenc = (const float*)d_in[2];
  const float* wih  = (const float*)d_in[3];
  const float* whh  = (const float*)d_in[4];
  const float* wdec = (const float*)d_in[5];
  float* out = (float*)d_out;
  char* ws = (char*)d_ws;

  u16* whh_hi = (u16*)(ws);                       // 33,554,432 B
  u16* whh_lo = (u16*)(ws + 33554432);            // 33,554,432 B
  u16* wdec_b = (u16*)(ws + 67108864);            //  4,194,304 B
  u16* h0hi   = (u16*)(ws + 71303168);            //  1,048,576 B
  u16* h0lo   = (u16*)(ws + 72351744);            //  1,048,576 B
  u16* hlo0   = (u16*)(ws + 73400320);            //  1,048,576 B
  u16* hlo1   = (u16*)(ws + 74448896);            //  1,048,576 B
  u16* hs     = (u16*)(ws + 75497472);            // 104,857,600 B
  float* part = (float*)d_out;                    // 16 MB scratch until decode
  const size_t BNG = (size_t)BSZ * NG;

  split_kernel<<<dim3(16384), dim3(256), 0, stream>>>(whh, whh_hi, whh_lo, 4194304);
  conv_kernel<<<dim3(2048), dim3(256), 0, stream>>>(wdec, wdec_b, 524288);
  encode_kernel<<<dim3(16, 128), dim3(256), 0, stream>>>(p0, wenc, h0hi, h0lo);

  for (int t = 0; t < NT; ++t) {
    const u16* ahi = (t == 0) ? h0hi : hs + (size_t)(t - 1) * BNG;
    const u16* alo = (t == 0) ? h0lo : ((t & 1) ? hlo0 : hlo1);
    u16* ohi = hs + (size_t)t * BNG;
    u16* olo = (t & 1) ? hlo1 : hlo0;
    step_gemm<<<dim3(KS, 32), dim3(512), 0, stream>>>(whh_hi, whh_lo, ahi, alo, part);
    step_reduce<<<dim3(512), dim3(256), 0, stream>>>(part, v, wih, ohi, olo, t);
  }
  decode_kernel<<<dim3(200), dim3(512), 0, stream>>>(hs, wdec_b, out, 12800, -1);
}

// Round 3
// 1679.320 us; speedup vs baseline: 3.3278x; 1.4789x over previous
//
#include <hip/hip_runtime.h>

#define NG 4096
#define NP 512
#define BSZ 128
#define NT 100
#define KS 16
#define KBLK 256
#define KC 64

typedef _Float16 f16;
typedef __attribute__((ext_vector_type(8))) _Float16 half8;
typedef __attribute__((ext_vector_type(4))) _Float16 half4v;
typedef __attribute__((ext_vector_type(16))) float f32x16;

__device__ inline f32x16 mfma16(half8 a, half8 b, f32x16 c) {
  return __builtin_amdgcn_mfma_f32_32x32x16_f16(a, b, c, 0, 0, 0);
}
__device__ __forceinline__ void gload16(const void* g, void* l) {
  __builtin_amdgcn_global_load_lds(
      (const __attribute__((address_space(1))) void*)g,
      (__attribute__((address_space(3))) void*)l, 16, 0, 0);
}

// ---------------- prep: f32 -> fp16 ----------------
__global__ __launch_bounds__(256) void conv_f16(
    const float* __restrict__ src, f16* __restrict__ dst, int n4)
{
  int i = blockIdx.x * 256 + threadIdx.x;
  if (i >= n4) return;
  const float4 x = ((const float4*)src)[i];
  half4v h = { (f16)x.x, (f16)x.y, (f16)x.z, (f16)x.w };
  *(half4v*)&dst[(size_t)i * 4] = h;
}

// h0 = p0 @ W_enc^T (fp32 accum), stored fp16
__global__ __launch_bounds__(256) void encode_kernel(
    const float* __restrict__ p0, const float* __restrict__ wenc,
    f16* __restrict__ h0)
{
  __shared__ float sp[NP];
  const int b = blockIdx.y;
  const int g = blockIdx.x * 256 + threadIdx.x;
  for (int i = threadIdx.x; i < NP; i += 256) sp[i] = p0[(size_t)b * NP + i];
  __syncthreads();
  const float4* wr = (const float4*)(wenc + (size_t)g * NP);
  float acc = 0.f;
  #pragma unroll 8
  for (int p4 = 0; p4 < NP / 4; ++p4) {
    float4 ww = wr[p4];
    acc += ww.x * sp[4*p4] + ww.y * sp[4*p4+1] + ww.z * sp[4*p4+2] + ww.w * sp[4*p4+3];
  }
  h0[(size_t)b * NG + g] = (f16)acc;
}

// ---------------- recurrent step: K-split fp16 GEMM ----------------
// partial[ks][b][n] = sum_{k in slice} h[b][k] * Whh[n][k], fp16 single product.
// grid (KS=16, 32); 256 thr = 4 waves (2M x 2N), wave tile 64x64, 32x32x16 MFMA.
// LDS/buffer 32 KB: A[128][128B] + B[128][128B]; XOR-swizzle on 16B units:
// LDS[row][u] = G[row][u ^ (row&7)]; read byte-col ^= ((row&7)<<4).
__global__ __launch_bounds__(256, 2) void step_gemm(
    const f16* __restrict__ whh16, const f16* __restrict__ hprev,
    f16* __restrict__ part)
{
  __shared__ __align__(128) char lds[2 * 32768];
  const int tid = threadIdx.x;
  const int w = tid >> 6, lane = tid & 63;
  const int wm = w & 1, wn = w >> 1;
  const int l31 = lane & 31, hi = lane >> 5;
  const int n0 = blockIdx.y * 128;
  const int k0 = blockIdx.x * KBLK;

  const int lrow8 = lane >> 3;
  const int swz = ((lane & 7) ^ lrow8) * 16;
  const char* gA = (const char*)hprev;
  const char* gB = (const char*)(whh16 + (size_t)n0 * NG);

  f32x16 acc[2][2] = {};

  auto stage = [&](int buf, int c) {
    const size_t kb = (size_t)((k0 + c * KC) * 2) + swz;
    char* lb = lds + buf * 32768;
    #pragma unroll
    for (int j = 0; j < 4; ++j) {
      const int r = w * 32 + j * 8;
      gload16(gA + (size_t)(r + lrow8) * (NG * 2) + kb, lb + r * 128);
      gload16(gB + (size_t)(r + lrow8) * (NG * 2) + kb, lb + 16384 + r * 128);
    }
  };
  auto compute = [&](int buf) {
    const char* bA = lds + buf * 32768;
    const char* bB = bA + 16384;
    const int swr = (lane & 7) << 4;
    #pragma unroll
    for (int kk = 0; kk < 4; ++kk) {
      const int bc = (kk * 32 + (hi << 4)) ^ swr;
      half8 a0 = *(const half8*)(bA + (wm * 64 + l31) * 128 + bc);
      half8 a1 = *(const half8*)(bA + (wm * 64 + 32 + l31) * 128 + bc);
      half8 b0 = *(const half8*)(bB + (wn * 64 + l31) * 128 + bc);
      half8 b1 = *(const half8*)(bB + (wn * 64 + 32 + l31) * 128 + bc);
      acc[0][0] = mfma16(a0, b0, acc[0][0]);
      acc[0][1] = mfma16(a0, b1, acc[0][1]);
      acc[1][0] = mfma16(a1, b0, acc[1][0]);
      acc[1][1] = mfma16(a1, b1, acc[1][1]);
    }
  };

  stage(0, 0);
  __syncthreads();
  #pragma unroll 1
  for (int c = 0; c < 4; ++c) {
    if (c < 3) stage((c + 1) & 1, c + 1);
    compute(c & 1);
    __syncthreads();
  }

  // C/D 32x32: col = lane&31, row = (q&3) + 8*(q>>2) + 4*(lane>>5)  [verified]
  f16* po = part + (size_t)blockIdx.x * (BSZ * NG);
  #pragma unroll
  for (int mf = 0; mf < 2; ++mf) {
    #pragma unroll
    for (int q = 0; q < 16; ++q) {
      const int row = wm * 64 + mf * 32 + (q & 3) + 8 * (q >> 2) + 4 * hi;
      #pragma unroll
      for (int nf = 0; nf < 2; ++nf) {
        const int col = n0 + wn * 64 + nf * 32 + l31;
        po[(size_t)row * NG + col] = (f16)acc[mf][nf][q];
      }
    }
  }
}

// sum KS fp16 partials + vin bias + relu -> h fp16
__global__ __launch_bounds__(256) void step_reduce(
    const f16* __restrict__ part, const float* __restrict__ v,
    const float* __restrict__ wih, f16* __restrict__ hout, int t)
{
  const int i = blockIdx.x * 256 + threadIdx.x;   // 65536 threads x 8 elems
  const int b = i >> 9;
  const int gi = (i & 511) * 8;
  const half8* p = (const half8*)part + (((size_t)b * NG + gi) >> 3);
  float s[8];
  half8 q0 = p[0];
  #pragma unroll
  for (int j = 0; j < 8; ++j) s[j] = (float)q0[j];
  #pragma unroll
  for (int k = 1; k < KS; ++k) {
    half8 q = p[(size_t)k * (BSZ * NG / 8)];
    #pragma unroll
    for (int j = 0; j < 8; ++j) s[j] += (float)q[j];
  }
  const float2 vb = *(const float2*)&v[((size_t)b * NT + t) * 2];
  const float4* wr = (const float4*)(wih + (size_t)gi * 2);
  half8 h;
  #pragma unroll
  for (int j2 = 0; j2 < 4; ++j2) {
    const float4 ww = wr[j2];
    const float x0 = fmaxf(s[j2 * 2]     + vb.x * ww.x + vb.y * ww.y, 0.f);
    const float x1 = fmaxf(s[j2 * 2 + 1] + vb.x * ww.z + vb.y * ww.w, 0.f);
    h[j2 * 2]     = (f16)x0;
    h[j2 * 2 + 1] = (f16)x1;
  }
  *(half8*)&hout[(size_t)b * NG + gi] = h;
}

// ---------------- decode + fused log_softmax ----------------
// block: 64 rows x 512 cols; 8 waves, wave tile 64x64 (w = col group).
__global__ __launch_bounds__(512, 2) void decode_kernel(
    const f16* __restrict__ hs, const f16* __restrict__ wdec16,
    float* __restrict__ out)
{
  __shared__ __align__(128) char lds[2 * 73728];   // [A 8K | B 64K] x2
  __shared__ float redm[8][64];
  __shared__ float reds[8][64];
  __shared__ float gLS[64];
  const int tid = threadIdx.x;
  const int w = tid >> 6, lane = tid & 63;
  const int l31 = lane & 31, hi = lane >> 5;
  const int r0 = blockIdx.x * 64;

  const int lrow8 = lane >> 3;
  const int swz = ((lane & 7) ^ lrow8) * 16;
  const char* gA = (const char*)(hs + (size_t)r0 * NG);
  const char* gB = (const char*)wdec16;

  f32x16 acc[2][2] = {};

  auto stage = [&](int buf, int c) {
    const size_t kb = (size_t)(c * 128) + swz;
    char* lb = lds + buf * 73728;
    gload16(gA + (size_t)(w * 8 + lrow8) * (NG * 2) + kb, lb + w * 1024);
    #pragma unroll
    for (int j = 0; j < 8; ++j) {
      const int r = w * 64 + j * 8;
      gload16(gB + (size_t)(r + lrow8) * (NG * 2) + kb, lb + 8192 + r * 128);
    }
  };
  auto compute = [&](int buf) {
    const char* bA = lds + buf * 73728;
    const char* bB = bA + 8192;
    const int swr = (lane & 7) << 4;
    #pragma unroll
    for (int kk = 0; kk < 4; ++kk) {
      const int bc = (kk * 32 + (hi << 4)) ^ swr;
      half8 a0 = *(const half8*)(bA + l31 * 128 + bc);
      half8 a1 = *(const half8*)(bA + (32 + l31) * 128 + bc);
      half8 b0 = *(const half8*)(bB + (w * 64 + l31) * 128 + bc);
      half8 b1 = *(const half8*)(bB + (w * 64 + 32 + l31) * 128 + bc);
      acc[0][0] = mfma16(a0, b0, acc[0][0]);
      acc[0][1] = mfma16(a0, b1, acc[0][1]);
      acc[1][0] = mfma16(a1, b0, acc[1][0]);
      acc[1][1] = mfma16(a1, b1, acc[1][1]);
    }
  };

  stage(0, 0);
  __syncthreads();
  #pragma unroll 1
  for (int c = 0; c < 64; ++c) {
    if (c < 63) stage((c + 1) & 1, c + 1);
    compute(c & 1);
    __syncthreads();
  }

  // ---- fused log_softmax over 512 cols ----
  // value (mf,nf,q): row_l = mf*32+(q&3)+8*(q>>2)+4*hi, col = w*64+nf*32+l31
  #pragma unroll
  for (int mf = 0; mf < 2; ++mf) {
    #pragma unroll
    for (int q = 0; q < 16; ++q) {
      float m = fmaxf(acc[mf][0][q], acc[mf][1][q]);
      #pragma unroll
      for (int d = 1; d < 32; d <<= 1) m = fmaxf(m, __shfl_xor(m, d));
      if (l31 == q) redm[w][mf * 32 + (q & 3) + 8 * (q >> 2) + 4 * hi] = m;
    }
  }
  __syncthreads();
  if (tid < 64) {
    float M = redm[0][tid];
    #pragma unroll
    for (int ww = 1; ww < 8; ++ww) M = fmaxf(M, redm[ww][tid]);
    gLS[tid] = M;
  }
  __syncthreads();
  #pragma unroll
  for (int mf = 0; mf < 2; ++mf) {
    #pragma unroll
    for (int q = 0; q < 16; ++q) {
      const int rl = mf * 32 + (q & 3) + 8 * (q >> 2) + 4 * hi;
      const float M = gLS[rl];
      float e = __expf(acc[mf][0][q] - M) + __expf(acc[mf][1][q] - M);
      #pragma unroll
      for (int d = 1; d < 32; d <<= 1) e += __shfl_xor(e, d);
      if (l31 == q) reds[w][rl] = e;
    }
  }
  __syncthreads();
  if (tid < 64) {
    float S = reds[0][tid];
    #pragma unroll
    for (int ww = 1; ww < 8; ++ww) S += reds[ww][tid];
    gLS[tid] = gLS[tid] + __logf(S);
  }
  __syncthreads();
  #pragma unroll
  for (int mf = 0; mf < 2; ++mf) {
    #pragma unroll
    for (int q = 0; q < 16; ++q) {
      const int rl = mf * 32 + (q & 3) + 8 * (q >> 2) + 4 * hi;
      const int r = r0 + rl;
      const int tt = r >> 7, b = r & 127;
      const float lg = gLS[rl];
      float* orow = out + ((size_t)b * NT + tt) * NP + w * 64 + l31;
      orow[0]  = acc[mf][0][q] - lg;
      orow[32] = acc[mf][1][q] - lg;
    }
  }
}

// ---------------- host ----------------

extern "C" void kernel_launch(void* const* d_in, const int* in_sizes, int n_in,
                              void* d_out, int out_size, void* d_ws, size_t ws_size,
                              hipStream_t stream)
{
  const float* v    = (const float*)d_in[0];
  const float* p0   = (const float*)d_in[1];
  const float* wenc = (const float*)d_in[2];
  const float* wih  = (const float*)d_in[3];
  const float* whh  = (const float*)d_in[4];
  const float* wdec = (const float*)d_in[5];
  float* out = (float*)d_out;
  char* ws = (char*)d_ws;

  f16* whh16  = (f16*)(ws);                 // 33,554,432 B
  f16* wdec16 = (f16*)(ws + 33554432);      //  4,194,304 B
  f16* h016   = (f16*)(ws + 37748736);      //  1,048,576 B
  f16* hs     = (f16*)(ws + 38797312);      // 104,857,600 B
  f16* part   = (f16*)d_out;                // 16.8 MB fp16 scratch until decode
  const size_t BNG = (size_t)BSZ * NG;

  conv_f16<<<dim3(16384), dim3(256), 0, stream>>>(whh, whh16, 4194304);
  conv_f16<<<dim3(2048), dim3(256), 0, stream>>>(wdec, wdec16, 524288);
  encode_kernel<<<dim3(16, 128), dim3(256), 0, stream>>>(p0, wenc, h016);

  for (int t = 0; t < NT; ++t) {
    const f16* hp = (t == 0) ? h016 : hs + (size_t)(t - 1) * BNG;
    step_gemm<<<dim3(KS, 32), dim3(256), 0, stream>>>(whh16, hp, part);
    step_reduce<<<dim3(256), dim3(256), 0, stream>>>(part, v, wih, hs + (size_t)t * BNG, t);
  }
  decode_kernel<<<dim3(200), dim3(512), 0, stream>>>(hs, wdec16, out);
}